// Round 1
// 193.874 us; speedup vs baseline: 1.0166x; 1.0166x over previous
//
#include <hip/hip_runtime.h>
#include <stdint.h>

// proj = einsum('bit,ih->tbh', x, W); scan: h=relu(p+0.8h(1-y)); y=thr(h+b,1).
// B=64, K=512, T=512, H=1024 fp32. Output: final y (64x1024).
//
// R6: pre-pass roofline fix. fused_main = 104us of the 197us iteration; the
// ~93us remainder is the split pre-pass, which reads x with 4B/lane strided
// loads (lanes 0..3 share a column across 4 rows -> 4x64B segments/instr,
// ~1.5 TB/s effective on a 128MB / ~20us job). Replaced with a register-tile
// transpose-convert: float4 coalesced reads (4x256B contiguous per instr,
// full lines consumed in-block), per-thread 8k x 4col register subtile ->
// four h8 hi + four h8 lo stores forming dense 64B segments (dense 1KB per
// wave across the unrolled i-loop). W conversion merged into the same launch
// (grid z=32 slice). Output layout + arithmetic bit-identical to R5's
// split_fragorder (same 2^6 prescale, same fp16 rounding, same chunk
// swizzle), so fused_main is byte-for-byte untouched and absmax must hold.

#define NB 64
#define NK 512
#define NT 512
#define NH 1024

#define TB 256     // t per block tile
#define HB 256     // h per block tile
#define KK 32      // k per step

typedef _Float16 h8_t __attribute__((ext_vector_type(8)));
typedef float    f4_t __attribute__((ext_vector_type(4)));

#define AS1 __attribute__((address_space(1)))
#define AS3 __attribute__((address_space(3)))

__device__ __forceinline__ void async_copy16(const _Float16* g, _Float16* l) {
    __builtin_amdgcn_global_load_lds((const AS1 uint32_t*)g, (AS3 uint32_t*)l, 16, 0, 0);
}

// explicit full drain + barrier: belt-and-suspenders vs compiler waitcnt
// insertion around global_load_lds (proven-correct R2/R5 k-loop shape)
__device__ __forceinline__ void wait_all_barrier() {
    __builtin_amdgcn_s_waitcnt(0);   // vmcnt(0) expcnt(0) lgkmcnt(0)
    __syncthreads();
}

// ---- pre-pass (R6): fp32 [rows][C] -> fp16 hi/lo in fragment order
// out[(kt_global*C + col)*32 + (ck ^ ((col>>1)&3))*8 + j]
//   = src[row = kt_local*32 + ck*8 + j][col] * 2^6, split hi/lo.
// Block: 256 threads, tile 128 rows x 64 cols.
//   thread (u = tid>>4, cq = tid&15): reads 8 x float4 (rows u*8+j,
//   cols cq*4..cq*4+3) -> coalesced 4x256B per instr; writes 4 hi + 4 lo
//   h8 chunks -> dense 64B segments per instr, dense 1KB per wave.
// Grid (16, 4, 33): z<32 -> x (two batches per z), z==32 -> W.
__global__ __launch_bounds__(256) void split_tc(
    const float* __restrict__ X, const float* __restrict__ Wm,
    _Float16* __restrict__ xhi, _Float16* __restrict__ xlo,
    _Float16* __restrict__ whi, _Float16* __restrict__ wlo)
{
    const int tid = threadIdx.x;
    const int cq  = tid & 15;     // col quad 0..15
    const int u   = tid >> 4;     // row octet 0..15

    const float* src;
    _Float16 *dhi, *dlo;
    int C, col0, row0, ktbase;

    if (blockIdx.z < 32) {
        // x slice: two batches per z plane
        const int idx = blockIdx.y * 16 + blockIdx.x;   // 0..63
        const int b   = blockIdx.z * 2 + (idx >> 5);    // 0..63
        const int i5  = idx & 31;
        const int bx  = i5 & 7;                          // col tile 0..7
        const int by  = i5 >> 3;                         // row tile 0..3
        C      = NT;                                     // 512
        src    = X + (size_t)b * NK * NT;
        dhi    = xhi;  dlo = xlo;
        col0   = bx * 64;
        row0   = by * 128;
        ktbase = b * 16 + by * 4;
    } else {
        // W slice: 16 col tiles x 4 row tiles
        const int bx = blockIdx.x;                       // 0..15
        const int by = blockIdx.y;                       // 0..3
        C      = NH;                                     // 1024
        src    = Wm;
        dhi    = whi;  dlo = wlo;
        col0   = bx * 64;
        row0   = by * 128;
        ktbase = by * 4;
    }

    const float* s = src + (size_t)(row0 + u * 8) * C + col0 + cq * 4;

    f4_t v[8];
    #pragma unroll
    for (int j = 0; j < 8; ++j)
        v[j] = *(const f4_t*)(s + (size_t)j * C);

    const int kt = ktbase + (u >> 2);
    const int ck = u & 3;

    #pragma unroll
    for (int i = 0; i < 4; ++i) {
        h8_t hi, lo;
        #pragma unroll
        for (int j = 0; j < 8; ++j) {
            float f = v[j][i] * 64.0f;       // 2^6 pre-scale (matches R5)
            _Float16 hh = (_Float16)f;
            hi[j] = hh;
            lo[j] = (_Float16)(f - (float)hh);
        }
        const int col = col0 + cq * 4 + i;
        const int ckp = ck ^ ((col >> 1) & 3);
        const size_t off = ((size_t)kt * C + col) * 32 + (size_t)ckp * 8;
        *(h8_t*)(dhi + off) = hi;
        *(h8_t*)(dlo + off) = lo;
    }
}

// ---------------- main fused kernel (unchanged from R5) ----------------
__global__ __launch_bounds__(512, 2) void fused_main(
    const _Float16* __restrict__ xhi, const _Float16* __restrict__ xlo,
    const _Float16* __restrict__ whi, const _Float16* __restrict__ wlo,
    const float* __restrict__ bias, float* __restrict__ out)
{
    __shared__ __align__(16) _Float16 Ahi[TB * KK];  // 16 KB
    __shared__ __align__(16) _Float16 Alo[TB * KK];  // 16 KB
    __shared__ __align__(16) _Float16 Bhi[HB * KK];  // 16 KB
    __shared__ __align__(16) _Float16 Blo[HB * KK];  // 16 KB
    __shared__ float P[2][64][132];                  // 67,584 B; total 133,120

    const int tid  = threadIdx.x;
    const int lane = tid & 63;
    const int wid  = tid >> 6;     // 0..7
    const int l15  = lane & 15;
    const int lq   = lane >> 4;    // 0..3
    const int wm   = wid >> 1;     // t quarter 0..3
    const int wn   = wid & 1;      // h half 0..1

    const int b  = blockIdx.x;
    const int h0 = blockIdx.y * HB;

    // fragment LDS offsets (halfs); chunk swizzle matches pre-pass
    const int sw   = (l15 >> 1) & 3;
    const int aoff = ((wm * 64 + l15) * 4 + (lq ^ sw)) * 8;   // + mi*512
    const int boff = ((wn * 128 + l15) * 4 + (lq ^ sw)) * 8;  // + ni*512

    float hs = 0.0f, ys = 0.0f, bv = 0.0f;
    if (tid < HB) bv = bias[h0 + tid];

    const float INV_SCALE = 1.0f / 4096.0f;   // undo 2^6 x 2^6 operand scales

    // stage tile (tt, kt): 4 arrays x 1024 16B-chunks, 512 threads x 2.
    // LDS dest = wave-uniform base + lane*16 (global_load_lds constraint).
    auto stage = [&](int tt, int kt) {
        const _Float16* ga_hi = xhi + ((size_t)(b * 16 + kt) * NT + tt) * KK;
        const _Float16* ga_lo = xlo + ((size_t)(b * 16 + kt) * NT + tt) * KK;
        const _Float16* gb_hi = whi + ((size_t)kt * NH + h0) * KK;
        const _Float16* gb_lo = wlo + ((size_t)kt * NH + h0) * KK;
        #pragma unroll
        for (int c = 0; c < 2; ++c) {
            const int ch = tid + c * 512;
            async_copy16(ga_hi + ch * 8, &Ahi[ch * 8]);
            async_copy16(ga_lo + ch * 8, &Alo[ch * 8]);
            async_copy16(gb_hi + ch * 8, &Bhi[ch * 8]);
            async_copy16(gb_lo + ch * 8, &Blo[ch * 8]);
        }
    };

    f4_t acc[4][8];

    for (int tt0 = 0; tt0 < NT; tt0 += TB) {
        #pragma unroll
        for (int mi = 0; mi < 4; ++mi)
            #pragma unroll
            for (int ni = 0; ni < 8; ++ni) {
                f4_t z = {0.f, 0.f, 0.f, 0.f};
                acc[mi][ni] = z;
            }

        for (int kt = 0; kt < NK / KK; ++kt) {
            stage(tt0, kt);       // proven shape: stage at top...
            wait_all_barrier();   // ...drain + barrier, then consume

            h8_t bh[8], bl[8];
            #pragma unroll
            for (int ni = 0; ni < 8; ++ni) {
                bh[ni] = *(const h8_t*)(&Bhi[boff + ni * 512]);
                bl[ni] = *(const h8_t*)(&Blo[boff + ni * 512]);
            }
            #pragma unroll
            for (int mi = 0; mi < 4; ++mi) {
                h8_t ah = *(const h8_t*)(&Ahi[aoff + mi * 512]);
                h8_t al = *(const h8_t*)(&Alo[aoff + mi * 512]);
                #pragma unroll
                for (int ni = 0; ni < 8; ++ni) {
                    acc[mi][ni] = __builtin_amdgcn_mfma_f32_16x16x32_f16(ah, bh[ni], acc[mi][ni], 0, 0, 0);
                    acc[mi][ni] = __builtin_amdgcn_mfma_f32_16x16x32_f16(ah, bl[ni], acc[mi][ni], 0, 0, 0);
                    acc[mi][ni] = __builtin_amdgcn_mfma_f32_16x16x32_f16(al, bh[ni], acc[mi][ni], 0, 0, 0);
                }
            }

            wait_all_barrier();   // all lanes' frag reads done before next stage
        }

        // epilogue: 4 t-subtiles x 64; both h-halves concurrently (P[0],P[1])
        #pragma unroll 1
        for (int sub = 0; sub < 4; ++sub) {
            if (wm == sub) {
                float (*Pb)[132] = P[wn];
                #pragma unroll
                for (int mi = 0; mi < 4; ++mi)
                    #pragma unroll
                    for (int ni = 0; ni < 8; ++ni)
                        #pragma unroll
                        for (int r = 0; r < 4; ++r)
                            Pb[mi * 16 + lq * 4 + r][ni * 16 + l15] = acc[mi][ni][r] * INV_SCALE;
            }
            __syncthreads();
            if (tid < HB) {
                const float (*Pb)[132] = P[tid >> 7];
                const int c = tid & 127;
                #pragma unroll 8
                for (int m = 0; m < 64; ++m) {
                    float p = Pb[m][c];
                    float pre = p + 0.8f * hs * (1.0f - ys);
                    hs = pre > 0.0f ? pre : 0.0f;
                    float z = hs + bv;
                    ys = (z > 1.0f) ? z : 0.0f;
                }
            }
            __syncthreads();   // scan done before next sub overwrites P
        }
    }

    if (tid < HB)
        out[(size_t)b * NH + h0 + tid] = ys;
}

extern "C" void kernel_launch(void* const* d_in, const int* in_sizes, int n_in,
                              void* d_out, int out_size, void* d_ws, size_t ws_size,
                              hipStream_t stream) {
    const float* x    = (const float*)d_in[0];  // [64][512][512]
    const float* W    = (const float*)d_in[1];  // [512][1024]
    const float* bias = (const float*)d_in[2];  // [1024]
    float* out = (float*)d_out;

    _Float16* xhi = (_Float16*)d_ws;
    _Float16* xlo = xhi + (size_t)NB * NK * NT;
    _Float16* whi = xlo + (size_t)NB * NK * NT;
    _Float16* wlo = whi + (size_t)NK * NH;

    split_tc<<<dim3(16, 4, 33), 256, 0, stream>>>(x, W, xhi, xlo, whi, wlo);
    fused_main<<<dim3(NB, NH / HB), 512, 0, stream>>>(xhi, xlo, whi, wlo, bias, out);
}